// Round 9
// baseline (107.590 us; speedup 1.0000x reference)
//
#include <hip/hip_runtime.h>

#define NB 16           // B images
#define NP 16000        // proposals per image
#define NG 256          // gt boxes per image
#define NM (NP + NG)    // proposals + gt = 16256 = 128*127
#define NSTRIP 254      // NM / 64
#define NS 512          // samples per image
#define NCLS 91
#define SL1_BETA (1.0f/9.0f)
#define MATCH_BLOCKS (127 * NB)     // 2032
#define STATS_BLOCKS 32
#define K1_BLOCKS (MATCH_BLOCKS + STATS_BLOCKS)
#define K2_BLOCKS 32

// ---------------------------------------------------------------------------
// K1: fused match + per-image sample (last-done block) + softmax stats.
//  - blocks [0, 2032): R8 match body (2 threads/proposal, 128 GTs each,
//    exact predicate 3*inter >= ap+garea, shfl_xor(1) half-merge, first-max
//    tie rule). After posinfo writes: per-image release-fence + counter;
//    the 127th block of an image acquires and runs the sample phase.
//  - blocks [2032, 2064): per-row logsumexp stats (mx + log(sum exp)) for
//    all 8192 rows (independent of match).
// ---------------------------------------------------------------------------
__global__ __launch_bounds__(256) void k1_kernel(
    const float4* __restrict__ props4,      // [NB*NP]
    const float4* __restrict__ gt4,         // [NB*NG]
    const int*    __restrict__ gt_labels,   // [NB*NG]
    const float*  __restrict__ gt_thetas,   // [NB*NG]
    const float*  __restrict__ logits,      // [NB*NS, NCLS]
    unsigned int* __restrict__ posinfo,     // [NB*NM]
    float*        __restrict__ stats,       // [NB*NS]
    unsigned int* __restrict__ imgcnt,      // [NB*32] (stride 32: own line)
    int*          __restrict__ labels_out,  // [NB*NS]
    float*        __restrict__ regt_out)    // [NB*NS*5]
{
    const int bid = blockIdx.x;
    const int tid = threadIdx.x;
    const int lane = tid & 63;
    const int wid  = tid >> 6;

    if (bid >= MATCH_BLOCKS) {
        // ---- softmax stats: wave-per-row, 64 rows/wave ----
        const int gw = (bid - MATCH_BLOCKS) * 4 + wid;      // 0..127
        for (int r = gw; r < NB * NS; r += STATS_BLOCKS * 4) {
            const float* row = logits + (size_t)r * NCLS;
            float a = (lane < NCLS)      ? row[lane]      : -3.0e38f;
            float c = (lane + 64 < NCLS) ? row[lane + 64] : -3.0e38f;
            float mx = fmaxf(a, c);
            #pragma unroll
            for (int o = 32; o; o >>= 1) mx = fmaxf(mx, __shfl_xor(mx, o, 64));
            float ss = 0.0f;
            if (lane < NCLS)      ss += expf(a - mx);
            if (lane + 64 < NCLS) ss += expf(c - mx);
            #pragma unroll
            for (int o = 32; o; o >>= 1) ss += __shfl_xor(ss, o, 64);
            if (lane == 0) stats[r] = mx + logf(ss);
        }
        return;
    }

    // ---- match ----
    __shared__ float4   gbox[NG];      // 4 KB
    __shared__ float    gar[NG];       // 1 KB
    __shared__ int      glab[NG];      // 1 KB
    __shared__ unsigned qst[256][5];   // 5 KB (stride 5: coprime to banks)
    __shared__ int      sampled[NS];   // 2 KB (sample phase)
    __shared__ int      wsum[4];
    __shared__ int      amLast;

    const int img = bid / 127;
    const int s   = bid % 127;

    {   // 256 threads load 256 gts
        const float4 v = gt4[(size_t)img * NG + tid];
        gbox[tid] = v;
        gar[tid]  = (v.z - v.x) * (v.w - v.y);
        glab[tid] = gt_labels[img * NG + tid];
    }
    __syncthreads();

    const int h     = tid & 1;                 // GT half (0: g<128, 1: g>=128)
    const int p     = tid >> 1;                // proposal-in-block 0..127
    const int j     = s * 128 + p;             // < NM (127*128 = NM)
    const int gbase = h * 128;

    const float4 pb = (j < NP) ? props4[(size_t)img * NP + j]
                               : gt4[(size_t)img * NG + (j - NP)];
    const float ap = (pb.z - pb.x) * (pb.w - pb.y);

    int qcnt = 0, gf = -1;
    for (int w = 0; w < 4; ++w) {
        unsigned m = 0;
        #pragma unroll
        for (int t = 0; t < 32; ++t) {
            const int g = gbase + w * 32 + t;
            const float4 gb = gbox[g];
            const float  ga = gar[g];
            float lx = fmaxf(gb.x, pb.x), ly = fmaxf(gb.y, pb.y);
            float rx = fminf(gb.z, pb.z), ry = fminf(gb.w, pb.w);
            float ww = fmaxf(rx - lx, 0.0f), hh = fmaxf(ry - ly, 0.0f);
            float inter = ww * hh;
            float tt = ga + ap;
            if (fmaf(inter, 3.0f, -tt) >= 0.0f) m |= (1u << t);
        }
        qst[tid][w] = m;
        if (qcnt == 0 && m) gf = w * 32 + (__ffs(m) - 1);
        qcnt += __popc(m);
    }

    float ib = -1.0f, ub = 1.0f;
    int   gstar = -1;
    if (qcnt == 1) {
        const int g = gbase + gf;
        const float4 gb = gbox[g];
        float lx = fmaxf(gb.x, pb.x), ly = fmaxf(gb.y, pb.y);
        float rx = fminf(gb.z, pb.z), ry = fminf(gb.w, pb.w);
        float ww = fmaxf(rx - lx, 0.0f), hh = fmaxf(ry - ly, 0.0f);
        ib = ww * hh;
        ub = (gar[g] + ap) - ib;
        gstar = g;
    } else if (qcnt > 1) {                     // rare: exact argmax, ascending g
        for (int w = 0; w < 4; ++w) {
            unsigned m = qst[tid][w];
            while (m) {
                int t = __ffs(m) - 1; m &= m - 1;
                int g = gbase + w * 32 + t;
                const float4 gb = gbox[g];
                float lx = fmaxf(gb.x, pb.x), ly = fmaxf(gb.y, pb.y);
                float rx = fminf(gb.z, pb.z), ry = fminf(gb.w, pb.w);
                float ww = fmaxf(rx - lx, 0.0f), hh = fmaxf(ry - ly, 0.0f);
                float inter = ww * hh;
                float u = (gar[g] + ap) - inter;
                if (inter * ub > ib * u) { ib = inter; ub = u; gstar = g; }
            }
        }
    }

    // merge the two halves (partner lane = lane^1)
    const int   oq  = __shfl_xor(qcnt, 1, 64);
    const float oib = __shfl_xor(ib, 1, 64);
    const float oub = __shfl_xor(ub, 1, 64);
    const int   og  = __shfl_xor(gstar, 1, 64);
    const int qtot = qcnt + oq;
    int gm;
    if (qcnt > 0 && oq > 0) {
        bool otherWins;
        if (h == 0) otherWins = (oib * ub > ib * oub);    // upper strictly better
        else        otherWins = !(ib * oub > oib * ub);   // lower unless self strictly better
        gm = otherWins ? og : gstar;
    } else {
        gm = (qcnt > 0) ? gstar : og;
    }

    if (h == 0) {
        unsigned info = 0;
        if (qtot > 0) info = ((unsigned)gm << 16) | (unsigned)glab[gm];
        posinfo[(size_t)img * NM + j] = info;
    }

    // ---- last-done block of this image runs the sample phase ----
    __syncthreads();
    if (tid == 0) {
        __threadfence();                                  // release posinfo
        unsigned old = atomicAdd(&imgcnt[img * 32], 1u);
        amLast = (old == 126u);
    }
    __syncthreads();
    if (!amLast) return;
    __threadfence();                                      // acquire others' posinfo

    const unsigned* P = posinfo + (size_t)img * NM;
    const int base = tid * 64;

    unsigned long long pm = 0ull;
    int cn = 0;
    if (tid < NSTRIP) {
        const uint4* Pv = reinterpret_cast<const uint4*>(P + base);
        #pragma unroll
        for (int q = 0; q < 16; ++q) {
            uint4 v = Pv[q];
            int e = q * 4;
            if (v.x) pm |= 1ull << (e + 0);
            if (v.y) pm |= 1ull << (e + 1);
            if (v.z) pm |= 1ull << (e + 2);
            if (v.w) pm |= 1ull << (e + 3);
        }
        cn = 64 - __popcll(pm);
    }
    int cp = (tid < NSTRIP) ? __popcll(pm) : 0;
    int val  = (cp << 16) | cn;
    int incl = val;
    #pragma unroll
    for (int off = 1; off < 64; off <<= 1) {
        int u = __shfl_up(incl, off, 64);
        if (lane >= off) incl += u;
    }
    if (lane == 63) wsum[wid] = incl;
    __syncthreads();
    int wbase = 0;
    #pragma unroll
    for (int w = 0; w < 4; ++w) if (w < wid) wbase += wsum[w];
    int tot  = wsum[0] + wsum[1] + wsum[2] + wsum[3];
    int excl = wbase + incl - val;
    int rp = excl >> 16, rn = excl & 0xffff;
    int posT = tot >> 16, negT = tot & 0xffff;
    int np = posT < 128 ? posT : 128;          // n_pos = min(pos_total, S/4)
    int nn = NS - np; if (nn > negT) nn = negT;

    if (tid < NSTRIP) {
        #pragma unroll 4
        for (int e = 0; e < 64; ++e) {
            int idx = base + e;
            if ((pm >> e) & 1ull) {
                if (rp < np) sampled[rp + (rn < nn ? rn : nn)] = idx;
                rp++;
            } else {
                if (rn < nn) sampled[rn + (rp < np ? rp : np)] = idx;
                rn++;
            }
        }
    }
    __syncthreads();
    // Fallback fill (unreachable with this data): unselected ascending.
    if (tid == 0 && np + nn < NS) {
        int cpp = 0, cnn = 0, i = np + nn;
        for (int idx = 0; idx < NM && i < NS; ++idx) {
            bool pp = P[idx] != 0;
            bool sel;
            if (pp) { sel = cpp < np; cpp++; } else { sel = cnn < nn; cnn++; }
            if (!sel) sampled[i++] = idx;
        }
    }
    __syncthreads();

    for (int i = tid; i < NS; i += 256) {
        int idx = sampled[i];
        unsigned info = P[idx];
        int lbl = 0;
        if (info) {
            int m = info >> 16; lbl = info & 0xffff;
            float4 pv = (idx < NP) ? props4[(size_t)img * NP + idx]
                                   : gt4[(size_t)img * NG + (idx - NP)];
            float4 rv = gt4[(size_t)img * NG + m];
            float pw = pv.z - pv.x, ph = pv.w - pv.y;
            float px = pv.x + 0.5f * pw, py = pv.y + 0.5f * ph;
            float gw = rv.z - rv.x, gh = rv.w - rv.y;
            float gx = rv.x + 0.5f * gw, gy = rv.y + 0.5f * gh;
            float* o = regt_out + ((size_t)img * NS + i) * 5;
            o[0] = 10.0f * (gx - px) / pw;
            o[1] = 10.0f * (gy - py) / ph;
            o[2] = 5.0f * logf(gw / pw);
            o[3] = 5.0f * logf(gh / ph);
            o[4] = gt_thetas[img * NG + m];
        }
        labels_out[img * NS + i] = lbl;
    }
}

// ---------------------------------------------------------------------------
// K2: label-dependent loss, thread-per-row + deterministic last-block reduce.
// cls_r = stats[r] - logits[r][lab];  box_r = smooth_l1 (lab>0 only).
// ---------------------------------------------------------------------------
__global__ __launch_bounds__(256) void k2_kernel(
    const float* __restrict__ logits,     // [N, 91]
    const float* __restrict__ boxreg,     // [N, 455]
    const int*   __restrict__ labs,       // [N]
    const float* __restrict__ regt,       // [N, 5]
    const float* __restrict__ stats,      // [N]
    float2* __restrict__ partials,        // [K2_BLOCKS]
    unsigned int* __restrict__ cnt2,
    float* __restrict__ out)              // [2]
{
    const int tid  = threadIdx.x;
    const int lane = tid & 63;
    const int wid  = tid >> 6;
    const int r    = blockIdx.x * 256 + tid;         // N = 32*256 = 8192

    const int lab = labs[r];
    float cls = stats[r] - logits[(size_t)r * NCLS + lab];
    float box = 0.0f;
    if (lab > 0) {
        const float* pr = boxreg + (size_t)r * (NCLS * 5) + lab * 5;
        const float* tg = regt + (size_t)r * 5;
        #pragma unroll
        for (int k = 0; k < 5; ++k) {
            float d  = pr[k] - tg[k];
            float ad = fabsf(d);
            box += (ad < SL1_BETA) ? 0.5f * d * d / SL1_BETA : ad - 0.5f * SL1_BETA;
        }
    }
    #pragma unroll
    for (int o = 32; o; o >>= 1) {
        cls += __shfl_xor(cls, o, 64);
        box += __shfl_xor(box, o, 64);
    }
    __shared__ float cc[4], bb[4];
    __shared__ int last;
    if (lane == 0) { cc[wid] = cls; bb[wid] = box; }
    __syncthreads();
    if (tid == 0) {
        partials[blockIdx.x] = make_float2(cc[0] + cc[1] + cc[2] + cc[3],
                                           bb[0] + bb[1] + bb[2] + bb[3]);
        __threadfence();
        last = (atomicAdd(cnt2, 1u) == K2_BLOCKS - 1);
    }
    __syncthreads();
    if (!last) return;
    __threadfence();
    if (tid < 64) {
        float2 v = (tid < K2_BLOCKS) ? partials[tid] : make_float2(0.f, 0.f);
        float c = v.x, bx = v.y;
        #pragma unroll
        for (int o = 32; o; o >>= 1) {
            c  += __shfl_xor(c, o, 64);
            bx += __shfl_xor(bx, o, 64);
        }
        if (tid == 0) {
            const float invN = 1.0f / (float)(NB * NS);
            out[0] = c * invN;
            out[1] = bx * invN;
        }
    }
}

// ---------------------------------------------------------------------------
extern "C" void kernel_launch(void* const* d_in, const int* in_sizes, int n_in,
                              void* d_out, int out_size, void* d_ws, size_t ws_size,
                              hipStream_t stream)
{
    const float* class_logits   = (const float*)d_in[0];  // [NB*NS, 91]
    const float* box_regression = (const float*)d_in[1];  // [NB*NS, 455]
    const float4* props4        = (const float4*)d_in[2]; // [NB, NP]
    const float4* gt4           = (const float4*)d_in[3]; // [NB, NG]
    const float* gt_thetas      = (const float*)d_in[4];  // [NB, NG]
    const int*   gt_labels      = (const int*)d_in[5];    // [NB, NG]
    float* out = (float*)d_out;

    char* ws = (char*)d_ws;
    unsigned int* imgcnt = (unsigned int*)ws;              // 16*32 u32 (2 KB)
    unsigned int* cnt2   = (unsigned int*)(ws + 2048);     // 1 u32
    unsigned int* posinfo = (unsigned int*)(ws + 4096);    // NB*NM u32
    char* pend = ws + 4096 + (((size_t)NB * NM * 4 + 255) & ~255ull);
    float* stats = (float*)pend;                           // NB*NS f32
    int*   labs  = (int*)(pend + ((size_t)NB * NS * 4 + 256 & ~255ull));
    float* regt  = (float*)((char*)labs + ((size_t)NB * NS * 4 + 256 & ~255ull));
    float2* partials = (float2*)((char*)regt + ((size_t)NB * NS * 5 * 4 + 256 & ~255ull));

    hipMemsetAsync(ws, 0, 4096, stream);                   // zero counters each call
    hipLaunchKernelGGL(k1_kernel, dim3(K1_BLOCKS), dim3(256), 0, stream,
                       props4, gt4, gt_labels, gt_thetas, class_logits,
                       posinfo, stats, imgcnt, labs, regt);
    hipLaunchKernelGGL(k2_kernel, dim3(K2_BLOCKS), dim3(256), 0, stream,
                       class_logits, box_regression, labs, regt, stats,
                       partials, cnt2, out);
}

// Round 10
// 84.368 us; speedup vs baseline: 1.2752x; 1.2752x over previous
//
#include <hip/hip_runtime.h>

#define NB 16           // B images
#define NP 16000        // proposals per image
#define NG 256          // gt boxes per image
#define NM (NP + NG)    // proposals + gt = 16256
#define NSTRIP 254      // NM / 64
#define NS 512          // samples per image
#define NCLS 91
#define SL1_BETA (1.0f/9.0f)
#define LOSS_BLOCKS 128

__device__ __forceinline__ float rlf(float v, int l) {
    return __int_as_float(__builtin_amdgcn_readlane(__float_as_int(v), l));
}

// ---------------------------------------------------------------------------
// Kernel 1 (match): ZERO-LDS. Lane l holds GTs {l, l+64, l+128, l+192} in
// registers; the (wave-uniform) g-loop broadcasts each GT via v_readlane
// (VALU, no LDS pipe). Each thread: 2 proposals (jA, jA+256), ONLINE exact
// argmax via the R3-proven two-product compare inter*ub > ib*u (ascending g +
// strict improve == first-max tie rule). Positivity via the R5-proven exact
// predicate fmaf(ib,3,-t*) >= 0, t* = ga+ap of the argmax (tracked exactly).
// Output: packed (gstar<<16)|label, 0 = negative. grid = (32, NB) x 256.
// Block (0,0) zeroes the loss completion counter.
// ---------------------------------------------------------------------------
__global__ __launch_bounds__(256) void match_kernel(
    const float4* __restrict__ props4,      // [NB*NP]
    const float4* __restrict__ gt4,         // [NB*NG]
    const int*    __restrict__ gt_labels,   // [NB*NG]
    unsigned int* __restrict__ posinfo,     // [NB*NM]
    unsigned int* __restrict__ cnt2)        // loss last-block counter
{
    const int b    = blockIdx.y;
    const int tid  = threadIdx.x;
    const int lane = tid & 63;
    if (blockIdx.x == 0 && b == 0 && tid == 0) *cnt2 = 0;

    // distributed GT storage (every wave holds all 256 GTs across its lanes)
    const float4 g0 = gt4[(size_t)b * NG + lane];
    const float4 g1 = gt4[(size_t)b * NG + 64 + lane];
    const float4 g2 = gt4[(size_t)b * NG + 128 + lane];
    const float4 g3 = gt4[(size_t)b * NG + 192 + lane];
    const float  a0 = (g0.z - g0.x) * (g0.w - g0.y);
    const float  a1 = (g1.z - g1.x) * (g1.w - g1.y);
    const float  a2 = (g2.z - g2.x) * (g2.w - g2.y);
    const float  a3 = (g3.z - g3.x) * (g3.w - g3.y);

    const int jA = blockIdx.x * 512 + tid;          // always < NM (max 16127)
    const int jB = jA + 256;                        // invalid only last block,
    const bool vB = (jB < NM);                      // wave-uniform split

    const float4 pA = (jA < NP) ? props4[(size_t)b * NP + jA]
                                : gt4[(size_t)b * NG + (jA - NP)];
    float4 pB = make_float4(0.f, 0.f, 0.f, 0.f);
    if (vB) pB = (jB < NP) ? props4[(size_t)b * NP + jB]
                           : gt4[(size_t)b * NG + (jB - NP)];
    const float apA = (pA.z - pA.x) * (pA.w - pA.y);
    const float apB = (pB.z - pB.x) * (pB.w - pB.y);

    float ibA = -1.f, ubA = 1.f, tA = 0.f;  int gA = 0;
    float ibB = -1.f, ubB = 1.f, tB = 0.f;  int gB = 0;

#define GT_GROUP(GV, AV, KBASE)                                              \
    for (int l = 0; l < 64; ++l) {                                           \
        const float gx0 = rlf(GV.x, l), gy0 = rlf(GV.y, l);                  \
        const float gx1 = rlf(GV.z, l), gy1 = rlf(GV.w, l);                  \
        const float ga  = rlf(AV, l);                                        \
        {   /* proposal A */                                                 \
            float lx = fmaxf(gx0, pA.x), ly = fmaxf(gy0, pA.y);              \
            float rx = fminf(gx1, pA.z), ry = fminf(gy1, pA.w);              \
            float w  = fmaxf(rx - lx, 0.f), h = fmaxf(ry - ly, 0.f);         \
            float inter = w * h;                                             \
            float t = ga + apA;                                              \
            float u = t - inter;                                             \
            if (inter * ubA > ibA * u) {                                     \
                ibA = inter; ubA = u; tA = t; gA = (KBASE) + l; }            \
        }                                                                    \
        {   /* proposal B */                                                 \
            float lx = fmaxf(gx0, pB.x), ly = fmaxf(gy0, pB.y);              \
            float rx = fminf(gx1, pB.z), ry = fminf(gy1, pB.w);              \
            float w  = fmaxf(rx - lx, 0.f), h = fmaxf(ry - ly, 0.f);         \
            float inter = w * h;                                             \
            float t = ga + apB;                                              \
            float u = t - inter;                                             \
            if (inter * ubB > ibB * u) {                                     \
                ibB = inter; ubB = u; tB = t; gB = (KBASE) + l; }            \
        }                                                                    \
    }

    GT_GROUP(g0, a0, 0)
    GT_GROUP(g1, a1, 64)
    GT_GROUP(g2, a2, 128)
    GT_GROUP(g3, a3, 192)
#undef GT_GROUP

    {   // A: positive iff max IoU >= 0.5  <=>  3*ib >= t* (exact predicate)
        unsigned info = 0;
        if (fmaf(ibA, 3.0f, -tA) >= 0.0f)
            info = ((unsigned)gA << 16) | (unsigned)gt_labels[b * NG + gA];
        posinfo[(size_t)b * NM + jA] = info;
    }
    if (vB) {
        unsigned info = 0;
        if (fmaf(ibB, 3.0f, -tB) >= 0.0f)
            info = ((unsigned)gB << 16) | (unsigned)gt_labels[b * NG + gB];
        posinfo[(size_t)b * NM + jB] = info;
    }
}

// ---------------------------------------------------------------------------
// Kernel 2: per-image balanced sampler (deterministic first-k) + box encoding.
// grid = NB, block = 256. Thread t<254 rebuilds its 64-proposal posmask from
// posinfo (info != 0 <=> positive) via uint4 loads; nmask = ~pmask. One shfl
// block-scan (2 barriers), direct-slot writes. Encode only positives.
// (Unchanged from R8 — proven.)
// ---------------------------------------------------------------------------
__global__ __launch_bounds__(256) void sample_kernel(
    const float4* __restrict__ props4,
    const float4* __restrict__ gt4,
    const float*  __restrict__ gt_thetas,
    const unsigned int* __restrict__ posinfo,
    int*   __restrict__ labels_out,   // [NB*NS]
    float* __restrict__ regt_out)     // [NB*NS*5]
{
    __shared__ int sampled[NS];
    __shared__ int wsum[4];

    const int b    = blockIdx.x;
    const int tid  = threadIdx.x;
    const int lane = tid & 63;
    const int wid  = tid >> 6;
    const unsigned* P = posinfo + (size_t)b * NM;
    const int base = tid * 64;

    unsigned long long pm = 0ull;
    int cn = 0;
    if (tid < NSTRIP) {
        const uint4* Pv = reinterpret_cast<const uint4*>(P + base);
        #pragma unroll
        for (int q = 0; q < 16; ++q) {
            uint4 v = Pv[q];
            int e = q * 4;
            if (v.x) pm |= 1ull << (e + 0);
            if (v.y) pm |= 1ull << (e + 1);
            if (v.z) pm |= 1ull << (e + 2);
            if (v.w) pm |= 1ull << (e + 3);
        }
        cn = 64 - __popcll(pm);
    }
    int cp = (tid < NSTRIP) ? __popcll(pm) : 0;
    int val  = (cp << 16) | cn;
    int incl = val;
    #pragma unroll
    for (int off = 1; off < 64; off <<= 1) {
        int u = __shfl_up(incl, off, 64);
        if (lane >= off) incl += u;
    }
    if (lane == 63) wsum[wid] = incl;
    __syncthreads();
    int wbase = 0;
    #pragma unroll
    for (int w = 0; w < 4; ++w) if (w < wid) wbase += wsum[w];
    int tot  = wsum[0] + wsum[1] + wsum[2] + wsum[3];
    int excl = wbase + incl - val;
    int rp = excl >> 16, rn = excl & 0xffff;
    int posT = tot >> 16, negT = tot & 0xffff;
    int np = posT < 128 ? posT : 128;          // n_pos = min(pos_total, S/4)
    int nn = NS - np; if (nn > negT) nn = negT;

    if (tid < NSTRIP) {
        #pragma unroll 4
        for (int e = 0; e < 64; ++e) {
            int idx = base + e;
            if ((pm >> e) & 1ull) {
                if (rp < np) sampled[rp + (rn < nn ? rn : nn)] = idx;
                rp++;
            } else {
                if (rn < nn) sampled[rn + (rp < np ? rp : np)] = idx;
                rn++;
            }
        }
    }
    __syncthreads();
    // Fallback fill (unreachable with this data): unselected ascending.
    if (tid == 0 && np + nn < NS) {
        int cpp = 0, cnn = 0, i = np + nn;
        for (int idx = 0; idx < NM && i < NS; ++idx) {
            bool p = P[idx] != 0;
            bool sel;
            if (p) { sel = cpp < np; cpp++; } else { sel = cnn < nn; cnn++; }
            if (!sel) sampled[i++] = idx;
        }
    }
    __syncthreads();

    for (int i = tid; i < NS; i += 256) {
        int idx = sampled[i];
        unsigned info = P[idx];
        int lbl = 0;
        if (info) {
            int m = info >> 16; lbl = info & 0xffff;
            float4 pv = (idx < NP) ? props4[(size_t)b * NP + idx]
                                   : gt4[(size_t)b * NG + (idx - NP)];
            float4 rv = gt4[(size_t)b * NG + m];
            float pw = pv.z - pv.x, ph = pv.w - pv.y;
            float px = pv.x + 0.5f * pw, py = pv.y + 0.5f * ph;
            float gw = rv.z - rv.x, gh = rv.w - rv.y;
            float gx = rv.x + 0.5f * gw, gy = rv.y + 0.5f * gh;
            float* o = regt_out + ((size_t)b * NS + i) * 5;
            o[0] = 10.0f * (gx - px) / pw;
            o[1] = 10.0f * (gy - py) / ph;
            o[2] = 5.0f * logf(gw / pw);
            o[3] = 5.0f * logf(gh / ph);
            o[4] = gt_thetas[b * NG + m];
        }
        labels_out[b * NS + i] = lbl;
    }
}

// ---------------------------------------------------------------------------
// Kernel 3: fused CE + smooth-L1 + final reduce (last-done of 128 blocks;
// fixed-order partial sum -> deterministic). One wave per row, grid-stride.
// ---------------------------------------------------------------------------
__global__ __launch_bounds__(256) void loss_kernel(
    const float* __restrict__ logits,     // [N, 91]
    const float* __restrict__ boxreg,     // [N, 455]
    const int*   __restrict__ labels,     // [N]
    const float* __restrict__ regt,       // [N, 5]
    float2* __restrict__ partials,        // [LOSS_BLOCKS]
    unsigned int* __restrict__ cnt2,      // zeroed by match_kernel
    float* __restrict__ out)              // [2]
{
    const int wave  = threadIdx.x >> 6;
    const int lane  = threadIdx.x & 63;
    const int gwave = blockIdx.x * 4 + wave;
    const int NWAVE = LOSS_BLOCKS * 4;
    const int N     = NB * NS;

    float cls_acc = 0.0f, box_acc = 0.0f;

    for (int r = gwave; r < N; r += NWAVE) {
        const float* row = logits + (size_t)r * NCLS;
        float a = (lane < NCLS)      ? row[lane]      : -3.0e38f;
        float c = (lane + 64 < NCLS) ? row[lane + 64] : -3.0e38f;
        float mx = fmaxf(a, c);
        #pragma unroll
        for (int o = 32; o; o >>= 1) mx = fmaxf(mx, __shfl_xor(mx, o, 64));
        float ssum = 0.0f;
        if (lane < NCLS)      ssum += expf(a - mx);
        if (lane + 64 < NCLS) ssum += expf(c - mx);
        #pragma unroll
        for (int o = 32; o; o >>= 1) ssum += __shfl_xor(ssum, o, 64);

        int lab = labels[r];                               // uniform broadcast
        float xl = (lab < 64) ? __shfl(a, lab, 64) : __shfl(c, lab - 64, 64);
        if (lane == 0) cls_acc += -(xl - mx - logf(ssum));

        if (lab > 0) {                                     // uniform branch
            float d = 0.0f;
            if (lane < 5) {
                float pv = boxreg[(size_t)r * (NCLS * 5) + lab * 5 + lane];
                float tv = regt[(size_t)r * 5 + lane];
                d = pv - tv;
            }
            float ad = fabsf(d);
            float sl = (ad < SL1_BETA) ? 0.5f * d * d / SL1_BETA : ad - 0.5f * SL1_BETA;
            sl += __shfl_xor(sl, 4, 8);
            sl += __shfl_xor(sl, 2, 8);
            sl += __shfl_xor(sl, 1, 8);
            if (lane == 0) box_acc += sl;
        }
    }

    __shared__ float cpart[4], bpart[4];
    __shared__ int amLast;
    if (lane == 0) { cpart[wave] = cls_acc; bpart[wave] = box_acc; }
    __syncthreads();
    if (threadIdx.x == 0) {
        partials[blockIdx.x] = make_float2(cpart[0] + cpart[1] + cpart[2] + cpart[3],
                                           bpart[0] + bpart[1] + bpart[2] + bpart[3]);
        __threadfence();
        amLast = (atomicAdd(cnt2, 1u) == LOSS_BLOCKS - 1);
    }
    __syncthreads();
    if (!amLast) return;
    __threadfence();
    if (threadIdx.x < 64) {
        const int tid = threadIdx.x;
        float2 v0 = partials[tid];
        float2 v1 = partials[tid + 64];
        float c = v0.x + v1.x, bx = v0.y + v1.y;
        #pragma unroll
        for (int o = 32; o; o >>= 1) {
            c  += __shfl_xor(c, o, 64);
            bx += __shfl_xor(bx, o, 64);
        }
        if (tid == 0) {
            const float invN = 1.0f / (float)(NB * NS);
            out[0] = c * invN;
            out[1] = bx * invN;
        }
    }
}

// ---------------------------------------------------------------------------
extern "C" void kernel_launch(void* const* d_in, const int* in_sizes, int n_in,
                              void* d_out, int out_size, void* d_ws, size_t ws_size,
                              hipStream_t stream)
{
    const float* class_logits   = (const float*)d_in[0];  // [NB*NS, 91]
    const float* box_regression = (const float*)d_in[1];  // [NB*NS, 455]
    const float4* props4        = (const float4*)d_in[2]; // [NB, NP]
    const float4* gt4           = (const float4*)d_in[3]; // [NB, NG]
    const float* gt_thetas      = (const float*)d_in[4];  // [NB, NG]
    const int*   gt_labels      = (const int*)d_in[5];    // [NB, NG]
    float* out = (float*)d_out;

    char* ws = (char*)d_ws;
    unsigned int* cnt2 = (unsigned int*)ws;                // u32 (256 B pad)
    unsigned int* posinfo = (unsigned int*)(ws + 256);     // NB*NM u32
    char* pend = ws + 256 + (((size_t)NB * NM * 4 + 255) & ~255ull);
    int*   labs  = (int*)pend;                             // NB*NS
    float* regt  = (float*)(pend + (((size_t)NB * NS * 4 + 255) & ~255ull));
    float2* partials = (float2*)((char*)regt + (((size_t)NB * NS * 5 * 4 + 255) & ~255ull));

    hipLaunchKernelGGL(match_kernel, dim3(32, NB), dim3(256), 0, stream,
                       props4, gt4, gt_labels, posinfo, cnt2);
    hipLaunchKernelGGL(sample_kernel, dim3(NB), dim3(256), 0, stream,
                       props4, gt4, gt_thetas, posinfo, labs, regt);
    hipLaunchKernelGGL(loss_kernel, dim3(LOSS_BLOCKS), dim3(256), 0, stream,
                       class_logits, box_regression, labs, regt, partials, cnt2, out);
}

// Round 11
// 71.632 us; speedup vs baseline: 1.5020x; 1.1778x over previous
//
#include <hip/hip_runtime.h>

#define NB 16           // B images
#define NP 16000        // proposals per image
#define NG 256          // gt boxes per image
#define NM (NP + NG)    // proposals + gt = 16256 = 127*128
#define NSTRIP 254      // NM / 64
#define NS 512          // samples per image
#define NCLS 91
#define SL1_BETA (1.0f/9.0f)
#define MATCHX 127      // match blocks per image (128 proposals each)
#define STATSX 4        // stats blocks per image (appended on x)

// ---------------------------------------------------------------------------
// K1 = match + softmax-stats (independent block ranges).
// match (x < 127): 2 threads per proposal (h = tid&1 -> GT half), 128 GTs
//   each, ONLINE exact argmax in registers (R10-proven compare
//   inter*ub > ib*u, ascending g + strict improve = first-max tie rule;
//   halves merged via shfl_xor(1), lower half wins ties). Positivity via the
//   proven exact predicate fmaf(ib,3,-t*) >= 0. GT data in LDS, read as
//   wave-uniform 2-address broadcast (free). Output: (gstar<<16)|label, 0=neg.
// stats (x >= 127): per-row logsumexp mx+log(sum exp) for 128 rows/block.
// grid = (131, NB) x 256. No atomics, no fences.
// ---------------------------------------------------------------------------
__global__ __launch_bounds__(256) void k1_kernel(
    const float4* __restrict__ props4,      // [NB*NP]
    const float4* __restrict__ gt4,         // [NB*NG]
    const int*    __restrict__ gt_labels,   // [NB*NG]
    const float*  __restrict__ logits,      // [NB*NS, NCLS]
    unsigned int* __restrict__ posinfo,     // [NB*NM]
    float*        __restrict__ stats)       // [NB*NS]
{
    const int b    = blockIdx.y;
    const int bx   = blockIdx.x;
    const int tid  = threadIdx.x;
    const int lane = tid & 63;
    const int wid  = tid >> 6;

    if (bx >= MATCHX) {
        // ---- softmax stats: 64 blocks x 4 waves; 32 rows per wave ----
        const int sid = (bx - MATCHX) * NB + b;          // 0..63
        for (int rr = 0; rr < 32; ++rr) {
            const int r = sid * 128 + wid * 32 + rr;
            const float* row = logits + (size_t)r * NCLS;
            float a = (lane < NCLS)      ? row[lane]      : -3.0e38f;
            float c = (lane + 64 < NCLS) ? row[lane + 64] : -3.0e38f;
            float mx = fmaxf(a, c);
            #pragma unroll
            for (int o = 32; o; o >>= 1) mx = fmaxf(mx, __shfl_xor(mx, o, 64));
            float ss = 0.0f;
            if (lane < NCLS)      ss += expf(a - mx);
            if (lane + 64 < NCLS) ss += expf(c - mx);
            #pragma unroll
            for (int o = 32; o; o >>= 1) ss += __shfl_xor(ss, o, 64);
            if (lane == 0) stats[r] = mx + logf(ss);
        }
        return;
    }

    // ---- match ----
    __shared__ float4 gbox[NG];     // 4 KB
    __shared__ float  gar[NG];      // 1 KB

    {   // 256 threads load 256 gts
        const float4 v = gt4[(size_t)b * NG + tid];
        gbox[tid] = v;
        gar[tid]  = (v.z - v.x) * (v.w - v.y);
    }
    __syncthreads();

    const int h     = tid & 1;                 // GT half (0: g<128, 1: g>=128)
    const int j     = bx * 128 + (tid >> 1);   // proposal, < NM always
    const int gbase = h * 128;

    const float4 pb = (j < NP) ? props4[(size_t)b * NP + j]
                               : gt4[(size_t)b * NG + (j - NP)];
    const float ap = (pb.z - pb.x) * (pb.w - pb.y);

    float ib = -1.0f, ub = 1.0f, tt = 0.0f;   // best (inter, union, ga+ap)
    int   gs = 0;                              // argmax g (first iter always adopts)
    #pragma unroll 4
    for (int k = 0; k < 128; ++k) {
        const int g = gbase + k;
        const float4 gb = gbox[g];
        const float  ga = gar[g];
        float lx = fmaxf(gb.x, pb.x), ly = fmaxf(gb.y, pb.y);
        float rx = fminf(gb.z, pb.z), ry = fminf(gb.w, pb.w);
        float w  = fmaxf(rx - lx, 0.0f), hh = fmaxf(ry - ly, 0.0f);
        float inter = w * hh;
        float t = ga + ap;
        float u = t - inter;
        // inter/u > ib/ub  <=>  inter*ub > ib*u (u,ub > 0); ascending g +
        // strict improve == first-max tie rule within the half
        if (inter * ub > ib * u) { ib = inter; ub = u; tt = t; gs = g; }
    }

    // merge halves (partner = lane^1); lower half wins exact ties
    const float oib = __shfl_xor(ib, 1, 64);
    const float oub = __shfl_xor(ub, 1, 64);
    const float ott = __shfl_xor(tt, 1, 64);
    const int   og  = __shfl_xor(gs, 1, 64);
    bool otherWins;
    if (h == 0) otherWins = (oib * ub > ib * oub);    // upper strictly better
    else        otherWins = !(ib * oub > oib * ub);   // lower unless self strictly better
    const float fib = otherWins ? oib : ib;
    const float ftt = otherWins ? ott : tt;
    const int   fgm = otherWins ? og  : gs;

    if (h == 0) {
        unsigned info = 0;
        if (fmaf(fib, 3.0f, -ftt) >= 0.0f)   // exact: max IoU >= 0.5
            info = ((unsigned)fgm << 16) | (unsigned)gt_labels[b * NG + fgm];
        posinfo[(size_t)b * NM + j] = info;
    }
}

// ---------------------------------------------------------------------------
// K2: per-image balanced sampler (deterministic first-k) + box encoding.
// Unchanged from R8 (proven). grid = NB x 256.
// ---------------------------------------------------------------------------
__global__ __launch_bounds__(256) void sample_kernel(
    const float4* __restrict__ props4,
    const float4* __restrict__ gt4,
    const float*  __restrict__ gt_thetas,
    const unsigned int* __restrict__ posinfo,
    int*   __restrict__ labels_out,   // [NB*NS]
    float* __restrict__ regt_out)     // [NB*NS*5]
{
    __shared__ int sampled[NS];
    __shared__ int wsum[4];

    const int b    = blockIdx.x;
    const int tid  = threadIdx.x;
    const int lane = tid & 63;
    const int wid  = tid >> 6;
    const unsigned* P = posinfo + (size_t)b * NM;
    const int base = tid * 64;

    unsigned long long pm = 0ull;
    int cn = 0;
    if (tid < NSTRIP) {
        const uint4* Pv = reinterpret_cast<const uint4*>(P + base);
        #pragma unroll
        for (int q = 0; q < 16; ++q) {
            uint4 v = Pv[q];
            int e = q * 4;
            if (v.x) pm |= 1ull << (e + 0);
            if (v.y) pm |= 1ull << (e + 1);
            if (v.z) pm |= 1ull << (e + 2);
            if (v.w) pm |= 1ull << (e + 3);
        }
        cn = 64 - __popcll(pm);
    }
    int cp = (tid < NSTRIP) ? __popcll(pm) : 0;
    int val  = (cp << 16) | cn;
    int incl = val;
    #pragma unroll
    for (int off = 1; off < 64; off <<= 1) {
        int u = __shfl_up(incl, off, 64);
        if (lane >= off) incl += u;
    }
    if (lane == 63) wsum[wid] = incl;
    __syncthreads();
    int wbase = 0;
    #pragma unroll
    for (int w = 0; w < 4; ++w) if (w < wid) wbase += wsum[w];
    int tot  = wsum[0] + wsum[1] + wsum[2] + wsum[3];
    int excl = wbase + incl - val;
    int rp = excl >> 16, rn = excl & 0xffff;
    int posT = tot >> 16, negT = tot & 0xffff;
    int np = posT < 128 ? posT : 128;          // n_pos = min(pos_total, S/4)
    int nn = NS - np; if (nn > negT) nn = negT;

    if (tid < NSTRIP) {
        #pragma unroll 4
        for (int e = 0; e < 64; ++e) {
            int idx = base + e;
            if ((pm >> e) & 1ull) {
                if (rp < np) sampled[rp + (rn < nn ? rn : nn)] = idx;
                rp++;
            } else {
                if (rn < nn) sampled[rn + (rp < np ? rp : np)] = idx;
                rn++;
            }
        }
    }
    __syncthreads();
    // Fallback fill (unreachable with this data): unselected ascending.
    if (tid == 0 && np + nn < NS) {
        int cpp = 0, cnn = 0, i = np + nn;
        for (int idx = 0; idx < NM && i < NS; ++idx) {
            bool p = P[idx] != 0;
            bool sel;
            if (p) { sel = cpp < np; cpp++; } else { sel = cnn < nn; cnn++; }
            if (!sel) sampled[i++] = idx;
        }
    }
    __syncthreads();

    for (int i = tid; i < NS; i += 256) {
        int idx = sampled[i];
        unsigned info = P[idx];
        int lbl = 0;
        if (info) {
            int m = info >> 16; lbl = info & 0xffff;
            float4 pv = (idx < NP) ? props4[(size_t)b * NP + idx]
                                   : gt4[(size_t)b * NG + (idx - NP)];
            float4 rv = gt4[(size_t)b * NG + m];
            float pw = pv.z - pv.x, ph = pv.w - pv.y;
            float px = pv.x + 0.5f * pw, py = pv.y + 0.5f * ph;
            float gw = rv.z - rv.x, gh = rv.w - rv.y;
            float gx = rv.x + 0.5f * gw, gy = rv.y + 0.5f * gh;
            float* o = regt_out + ((size_t)b * NS + i) * 5;
            o[0] = 10.0f * (gx - px) / pw;
            o[1] = 10.0f * (gy - py) / ph;
            o[2] = 5.0f * logf(gw / pw);
            o[3] = 5.0f * logf(gh / ph);
            o[4] = gt_thetas[b * NG + m];
        }
        labels_out[b * NS + i] = lbl;
    }
}

// ---------------------------------------------------------------------------
// K3: label-dependent loss, thread-per-row (stats precomputed in K1).
// 32 blocks x 256; per-block float2 partial. No atomics.
// ---------------------------------------------------------------------------
__global__ __launch_bounds__(256) void loss_kernel(
    const float* __restrict__ logits,     // [N, 91]
    const float* __restrict__ boxreg,     // [N, 455]
    const int*   __restrict__ labs,       // [N]
    const float* __restrict__ regt,       // [N, 5]
    const float* __restrict__ stats,      // [N]
    float2* __restrict__ partials)        // [32]
{
    const int tid  = threadIdx.x;
    const int lane = tid & 63;
    const int wid  = tid >> 6;
    const int r    = blockIdx.x * 256 + tid;         // N = 32*256 = 8192

    const int lab = labs[r];
    float cls = stats[r] - logits[(size_t)r * NCLS + lab];
    float box = 0.0f;
    if (lab > 0) {
        const float* pr = boxreg + (size_t)r * (NCLS * 5) + lab * 5;
        const float* tg = regt + (size_t)r * 5;
        #pragma unroll
        for (int k = 0; k < 5; ++k) {
            float d  = pr[k] - tg[k];
            float ad = fabsf(d);
            box += (ad < SL1_BETA) ? 0.5f * d * d / SL1_BETA : ad - 0.5f * SL1_BETA;
        }
    }
    #pragma unroll
    for (int o = 32; o; o >>= 1) {
        cls += __shfl_xor(cls, o, 64);
        box += __shfl_xor(box, o, 64);
    }
    __shared__ float cc[4], bb[4];
    if (lane == 0) { cc[wid] = cls; bb[wid] = box; }
    __syncthreads();
    if (tid == 0)
        partials[blockIdx.x] = make_float2(cc[0] + cc[1] + cc[2] + cc[3],
                                           bb[0] + bb[1] + bb[2] + bb[3]);
}

// ---------------------------------------------------------------------------
// K4: reduce 32 float2 partials -> 2 outputs. 1 block x 64.
// ---------------------------------------------------------------------------
__global__ void final_kernel(const float2* __restrict__ partials,
                             float* __restrict__ out)
{
    const int tid = threadIdx.x;
    float2 v = (tid < 32) ? partials[tid] : make_float2(0.f, 0.f);
    float c = v.x, bx = v.y;
    #pragma unroll
    for (int o = 32; o; o >>= 1) {
        c  += __shfl_xor(c, o, 64);
        bx += __shfl_xor(bx, o, 64);
    }
    if (tid == 0) {
        const float invN = 1.0f / (float)(NB * NS);
        out[0] = c * invN;
        out[1] = bx * invN;
    }
}

// ---------------------------------------------------------------------------
extern "C" void kernel_launch(void* const* d_in, const int* in_sizes, int n_in,
                              void* d_out, int out_size, void* d_ws, size_t ws_size,
                              hipStream_t stream)
{
    const float* class_logits   = (const float*)d_in[0];  // [NB*NS, 91]
    const float* box_regression = (const float*)d_in[1];  // [NB*NS, 455]
    const float4* props4        = (const float4*)d_in[2]; // [NB, NP]
    const float4* gt4           = (const float4*)d_in[3]; // [NB, NG]
    const float* gt_thetas      = (const float*)d_in[4];  // [NB, NG]
    const int*   gt_labels      = (const int*)d_in[5];    // [NB, NG]
    float* out = (float*)d_out;

    char* ws = (char*)d_ws;
    unsigned int* posinfo = (unsigned int*)ws;             // NB*NM u32
    char* pend = ws + (((size_t)NB * NM * 4 + 255) & ~255ull);
    float* stats = (float*)pend;                           // NB*NS f32
    int*   labs  = (int*)(pend + (((size_t)NB * NS * 4 + 255) & ~255ull));
    float* regt  = (float*)((char*)labs + (((size_t)NB * NS * 4 + 255) & ~255ull));
    float2* partials = (float2*)((char*)regt + (((size_t)NB * NS * 5 * 4 + 255) & ~255ull));

    hipLaunchKernelGGL(k1_kernel, dim3(MATCHX + STATSX, NB), dim3(256), 0, stream,
                       props4, gt4, gt_labels, class_logits, posinfo, stats);
    hipLaunchKernelGGL(sample_kernel, dim3(NB), dim3(256), 0, stream,
                       props4, gt4, gt_thetas, posinfo, labs, regt);
    hipLaunchKernelGGL(loss_kernel, dim3(32), dim3(256), 0, stream,
                       class_logits, box_regression, labs, regt, stats, partials);
    hipLaunchKernelGGL(final_kernel, dim3(1), dim3(64), 0, stream, partials, out);
}